// Round 2
// baseline (35.162 us; speedup 1.0000x reference)
//
#include <hip/hip_runtime.h>

// GroupSort: out[:, 2k]   = min(x[:, 2k], x[:, 2k+1])
//            out[:, 2k+1] = max(x[:, 2k], x[:, 2k+1])
// x: (32, 256, 56, 56) f32 contiguous. Plane = 56*56 = 3136 floats = 784 float4.
// Pair of planes = 1568 float4. Total pair-vectors = 32*128*784 = 3,211,264.

#define HW4   784      // float4s per channel plane
#define PAIR4 1568     // float4s per channel pair (2 planes)

__device__ __forceinline__ void sort4(const float4& a, const float4& b,
                                      float4& lo, float4& hi) {
    lo.x = fminf(a.x, b.x); hi.x = fmaxf(a.x, b.x);
    lo.y = fminf(a.y, b.y); hi.y = fmaxf(a.y, b.y);
    lo.z = fminf(a.z, b.z); hi.z = fmaxf(a.z, b.z);
    lo.w = fminf(a.w, b.w); hi.w = fmaxf(a.w, b.w);
}

__global__ __launch_bounds__(256) void groupsort_kernel(const float4* __restrict__ x,
                                                        float4* __restrict__ out,
                                                        int total) {
    const int nthreads = gridDim.x * 256;
    int i = blockIdx.x * 256 + threadIdx.x;

    // Unrolled-by-2 grid-stride: 4 loads in flight per iteration.
    for (; i + nthreads < total; i += 2 * nthreads) {
        int i1 = i + nthreads;
        int p0 = i  / HW4, r0 = i  - p0 * HW4, b0 = p0 * PAIR4 + r0;
        int p1 = i1 / HW4, r1 = i1 - p1 * HW4, b1 = p1 * PAIR4 + r1;

        float4 a0 = x[b0];
        float4 c0 = x[b0 + HW4];
        float4 a1 = x[b1];
        float4 c1 = x[b1 + HW4];

        float4 lo0, hi0, lo1, hi1;
        sort4(a0, c0, lo0, hi0);
        sort4(a1, c1, lo1, hi1);

        out[b0]       = lo0;
        out[b0 + HW4] = hi0;
        out[b1]       = lo1;
        out[b1 + HW4] = hi1;
    }
    if (i < total) {
        int p0 = i / HW4, r0 = i - p0 * HW4, b0 = p0 * PAIR4 + r0;
        float4 a0 = x[b0];
        float4 c0 = x[b0 + HW4];
        float4 lo0, hi0;
        sort4(a0, c0, lo0, hi0);
        out[b0]       = lo0;
        out[b0 + HW4] = hi0;
    }
}

extern "C" void kernel_launch(void* const* d_in, const int* in_sizes, int n_in,
                              void* d_out, int out_size, void* d_ws, size_t ws_size,
                              hipStream_t stream) {
    const float4* x = (const float4*)d_in[0];
    float4* out = (float4*)d_out;
    int total = out_size / 8;            // pair-vectors
    groupsort_kernel<<<2048, 256, 0, stream>>>(x, out, total);
}

// Round 3
// 34.734 us; speedup vs baseline: 1.0123x; 1.0123x over previous
//
#include <hip/hip_runtime.h>

// GroupSort: out[:, 2k]   = min(x[:, 2k], x[:, 2k+1])
//            out[:, 2k+1] = max(x[:, 2k], x[:, 2k+1])
// x: (32, 256, 56, 56) f32 contiguous. Plane = 56*56 = 3136 floats = 784 float4.
// Total pair-vectors = 32*128*784 = 3,211,264.
//
// Stores are non-temporal (no-allocate): output must not evict the input
// from the 256 MB Infinity Cache — reads then stay L3-resident across
// graph replays (round-2 profile: FETCH was already only half the input).

#define HW4   784      // float4s per channel plane
#define PAIR4 1568     // float4s per channel pair (2 planes)

typedef float f32x4 __attribute__((ext_vector_type(4)));

__global__ __launch_bounds__(256) void groupsort_kernel(const f32x4* __restrict__ x,
                                                        f32x4* __restrict__ out,
                                                        int total) {
    int i = blockIdx.x * 256 + threadIdx.x;
    if (i >= total) return;
    int pair = i / HW4;
    int pos  = i - pair * HW4;
    int base = pair * PAIR4 + pos;

    f32x4 a = x[base];          // even channel
    f32x4 b = x[base + HW4];    // odd channel

    f32x4 lo, hi;
    lo[0] = fminf(a[0], b[0]); hi[0] = fmaxf(a[0], b[0]);
    lo[1] = fminf(a[1], b[1]); hi[1] = fmaxf(a[1], b[1]);
    lo[2] = fminf(a[2], b[2]); hi[2] = fmaxf(a[2], b[2]);
    lo[3] = fminf(a[3], b[3]); hi[3] = fmaxf(a[3], b[3]);

    __builtin_nontemporal_store(lo, &out[base]);
    __builtin_nontemporal_store(hi, &out[base + HW4]);
}

extern "C" void kernel_launch(void* const* d_in, const int* in_sizes, int n_in,
                              void* d_out, int out_size, void* d_ws, size_t ws_size,
                              hipStream_t stream) {
    const f32x4* x = (const f32x4*)d_in[0];
    f32x4* out = (f32x4*)d_out;
    int total = out_size / 8;            // pair-vectors
    int blocks = (total + 255) / 256;
    groupsort_kernel<<<blocks, 256, 0, stream>>>(x, out, total);
}